// Round 5
// baseline (661.363 us; speedup 1.0000x reference)
//
#include <hip/hip_runtime.h>
#include <cstdint>

// Board: 4096 x 4096 int32 in {0,1,2}  (0=empty, 1=black, 2=white)
// Outputs BOOLEAN -> int32 (0/1), concatenated flat in d_out:
//   bamboo_b, bamboo_w, tiger_b, tiger_w, etri_b, etri_w  -> each (4095,4095)
//   eye_b, eye_w                                          -> each (4094,4094)
//
// R15: OUTPUT-CENTRIC single kernel (no scratch).
//   R14 post-mortem: 578 us == fallback noise band -> ws_size likely < 16 MB,
//   fast path never ran, alignment theory still untested. This version tests
//   it without scratch: thread c owns flat output bytes c*16..c*16+15, so a
//   wave's store is a 1 KB full-line-aligned block (identical pattern to the
//   6.3 TB/s fill). Board neighborhood (3 rows x 5-6 cells) is read directly;
//   board = 64 MB -> LLC-resident across the 8 plane passes.
//   Theory: R12's 16B-aligned stores (row stride 16380 B) caused partial-line
//   L2 write-allocate RMW -> ~2.4 TB/s. Full-line stores -> ~6 TB/s.

#define BW 4096
#define W1 4095
#define W2 4094
#define N1 16769025u
#define N2 16760836u
#define TOTAL 134135822u        // 6*N1 + 2*N2
#define M55 0x5555u

typedef int i4a __attribute__((vector_size(16), aligned(16)));

struct Planes { unsigned pm[6]; unsigned em[2]; };

// m0/m1/m2: packed rows (2-bit fields, cell k at bits 2k..2k+1).
// Outputs at bit positions 2k, k=0..3. pm planes use m0,m1 cells 0..4;
// em (eyes) additionally use m1 cell 5 and m2 cells 0..4.
__device__ __forceinline__ Planes compute_swar(unsigned m0, unsigned m1, unsigned m2)
{
    const unsigned B0 = m0 & M55,        Wt = (m0 >> 1) & M55;
    const unsigned B1 = m1 & M55,        Wl = (m1 >> 1) & M55;
    const unsigned B2 = m2 & M55,        Wb = (m2 >> 1) & M55;
    const unsigned E0 = (B0 | Wt) ^ M55;
    const unsigned E1 = (B1 | Wl) ^ M55;

    const unsigned sB0 = B0 >> 2, sB1 = B1 >> 2;
    const unsigned sW0 = Wt >> 2, sW1 = Wl >> 2;
    const unsigned sE0 = E0 >> 2, sE1 = E1 >> 2;
    const unsigned sB2 = B2 >> 2, sW2 = Wb >> 2;

    const unsigned EaEd = E0 & sE1;              // diag pair both empty
    const unsigned EbEc = sE0 & E1;              // anti pair both empty
    const unsigned anyE = E0 | sE0 | E1 | sE1;   // >=1 empty corner

    Planes r;
    {   // black
        const unsigned P = B0 & sB0, Q = B1 & sB1;
        const unsigned Dg = B0 & sB1, Ag = sB0 & B1;
        const unsigned X = B0 & B1,  Y = sB0 & sB1;
        const unsigned ge2 = P | Q | Dg | Ag | X | Y;
        const unsigned ge3 = (P & (B1 | sB1)) | (Q & (B0 | sB0));
        r.pm[0] = (Dg & EbEc) | (Ag & EaEd);   // bamboo_b
        r.pm[2] = ge2 & anyE;                  // tiger_b
        r.pm[4] = ge3 & anyE;                  // etri_b
        r.em[0] = sE1 & sB0 & B1 & (B1 >> 4) & sB2;  // eye_b
    }
    {   // white
        const unsigned P = Wt & sW0, Q = Wl & sW1;
        const unsigned Dg = Wt & sW1, Ag = sW0 & Wl;
        const unsigned X = Wt & Wl,  Y = sW0 & sW1;
        const unsigned ge2 = P | Q | Dg | Ag | X | Y;
        const unsigned ge3 = (P & (Wl | sW1)) | (Q & (Wt | sW0));
        r.pm[1] = (Dg & EbEc) | (Ag & EaEd);
        r.pm[3] = ge2 & anyE;
        r.pm[5] = ge3 & anyE;
        r.em[1] = sE1 & sW0 & Wl & (Wl >> 4) & sW2;  // eye_w
    }
    return r;
}

__device__ __forceinline__ void decode(uint32_t e, uint32_t& p, uint32_t& row,
                                       uint32_t& col, uint32_t& width)
{
    if (e < 6u * N1) {
        p = e / N1;
        const uint32_t rem = e - p * N1;
        row = rem / W1;
        col = rem - row * W1;
        width = W1;
    } else {
        const uint32_t q  = e - 6u * N1;
        const uint32_t pp = q / N2;
        const uint32_t rem = q - pp * N2;
        p = 6u + pp;
        row = rem / W2;
        col = rem - row * W2;
        width = W2;
    }
}

// scalar single-output evaluation (rare path; all accesses in-bounds:
// p<6: row<=4094, col<=4094; p>=6: row<=4093, col<=4093)
__device__ __forceinline__ int one_out(const int* __restrict__ board,
                                       uint32_t p, uint32_t row, uint32_t col)
{
    if (p < 6u) {
        const int a = board[(size_t)row * BW + col];
        const int b = board[(size_t)row * BW + col + 1];
        const int c = board[(size_t)(row + 1) * BW + col];
        const int d = board[(size_t)(row + 1) * BW + col + 1];
        const int nb = (a == 1) + (b == 1) + (c == 1) + (d == 1);
        const int nw = (a == 2) + (b == 2) + (c == 2) + (d == 2);
        const int ne = 4 - nb - nw;
        switch (p) {
        case 0: return ((a==1 && d==1 && b==0 && c==0) || (b==1 && c==1 && a==0 && d==0));
        case 1: return ((a==2 && d==2 && b==0 && c==0) || (b==2 && c==2 && a==0 && d==0));
        case 2: return (nb >= 2 && ne >= 1);
        case 3: return (nw >= 2 && ne >= 1);
        case 4: return (nb == 3 && ne == 1);
        default: return (nw == 3 && ne == 1);
        }
    }
    const int st = (p == 6u) ? 1 : 2;
    const size_t r1 = (size_t)(row + 1) * BW;
    return (board[r1 + col + 1] == 0
         && board[(size_t)row * BW + col + 1] == st
         && board[(size_t)(row + 2) * BW + col + 1] == st
         && board[r1 + col] == st
         && board[r1 + col + 2] == st);
}

__global__ __launch_bounds__(256)
void direct_kernel(const int* __restrict__ board, int* __restrict__ out)
{
    const uint32_t c = blockIdx.x * 256u + threadIdx.x;  // chunk of 4 ints
    const uint32_t o = c * 4u;
    if (o >= TOTAL) return;

    uint32_t p, row, col, width;
    decode(o, p, row, col, width);

    if (col + 3u < width && o + 4u <= TOTAL) {
        // common case: 4 outputs in one row of one plane.
        // loads: p<6 -> rows row..row+1, cells col..col+4 (col<=4091 -> +4<=4095)
        //        p>=6 -> rows row..row+2, + cell col+5 of row+1 (col<=4089)
        const int* r0p = board + (size_t)row * BW + col;
        const int* r1p = r0p + BW;
        unsigned m0 = 0, m1 = 0, m2 = 0;
        #pragma unroll
        for (int k = 0; k < 5; ++k) {
            m0 |= ((unsigned)r0p[k]) << (2 * k);
            m1 |= ((unsigned)r1p[k]) << (2 * k);
        }
        if (p >= 6u) {                       // wave-uniform except at boundaries
            const int* r2p = r1p + BW;
            m1 |= ((unsigned)r1p[5]) << 10;
            #pragma unroll
            for (int k = 0; k < 5; ++k)
                m2 |= ((unsigned)r2p[k]) << (2 * k);
        }
        const Planes P = compute_swar(m0, m1, m2);
        unsigned w;
        switch (p) {                         // static select (no dyn indexing)
        case 0: w = P.pm[0]; break;  case 1: w = P.pm[1]; break;
        case 2: w = P.pm[2]; break;  case 3: w = P.pm[3]; break;
        case 4: w = P.pm[4]; break;  case 5: w = P.pm[5]; break;
        case 6: w = P.em[0]; break;  default: w = P.em[1]; break;
        }
        i4a s;
        s[0] = (int)(w & 1u);
        s[1] = (int)((w >> 2) & 1u);
        s[2] = (int)((w >> 4) & 1u);
        s[3] = (int)((w >> 6) & 1u);
        *(i4a*)(out + o) = s;                // 16B chunk of an aligned 1KB/wave block
    } else {
        // rare (~0.1%): row/plane crossing or final partial chunk
        int vals[4];
        #pragma unroll
        for (int k = 0; k < 4; ++k) {
            const uint32_t e = o + (uint32_t)k;
            if (e < TOTAL) {
                uint32_t pp, rr, cc, ww;
                decode(e, pp, rr, cc, ww);
                vals[k] = one_out(board, pp, rr, cc);
            } else vals[k] = 0;
        }
        if (o + 4u <= TOTAL) {
            i4a s; s[0] = vals[0]; s[1] = vals[1]; s[2] = vals[2]; s[3] = vals[3];
            *(i4a*)(out + o) = s;
        } else {
            for (uint32_t k = 0; o + k < TOTAL; ++k) out[o + k] = vals[k];
        }
    }
}

extern "C" void kernel_launch(void* const* d_in, const int* in_sizes, int n_in,
                              void* d_out, int out_size, void* d_ws, size_t ws_size,
                              hipStream_t stream) {
    const int* board = (const int*)d_in[0];
    int* out = (int*)d_out;

    const uint32_t chunks  = (TOTAL + 3u) / 4u;      // 33,533,956
    const uint32_t nblocks = (chunks + 255u) / 256u; // 130,993
    direct_kernel<<<dim3(nblocks, 1, 1), dim3(256, 1, 1), 0, stream>>>(board, out);
}

// Round 6
// 657.075 us; speedup vs baseline: 1.0065x; 1.0065x over previous
//
#include <hip/hip_runtime.h>
#include <cstdint>

// Board: 4096 x 4096 int32 in {0,1,2}  (0=empty, 1=black, 2=white)
// Outputs BOOLEAN -> int32 (0/1), concatenated flat in d_out:
//   bamboo_b, bamboo_w, tiger_b, tiger_w, etri_b, etri_w  -> each (4095,4095)
//   eye_b, eye_w                                          -> each (4094,4094)
//
// R16: flat output-centric (R15's aligned 1KB/wave stores) + VECTORIZED reads.
//   R15 post-mortem: 321 us kernel, worse than R12's 254. Cause: 10-16 scalar
//   dword loads/thread at 16B lane-stride = ~4x L1 amplification (~10 KB L1
//   per wave per 1 KB stored). The aligned-store theory was never isolated.
//   Key fact enabling the fix: within a plane+row, col mod 4 is WAVE-UNIFORM
//   (N1%4==1, W1%4==3 -> col == (row-p) mod 4), so each thread's 5-cell
//   window lies in exactly 2 aligned 16B chunks (base col-(col&3); windows
//   advance in steps of 4 from that base, so chunk 2 never crosses the row
//   end). Pack chunks, shift by 2*(col&3) -- R12's phase trick on the LOAD
//   side. Plus: per-plane switch computes only the needed motif formula.

#define BW 4096
#define W1 4095
#define W2 4094
#define N1 16769025u
#define N2 16760836u
#define TOTAL 134135822u        // 6*N1 + 2*N2
#define M55 0x5555u

typedef int i4a __attribute__((vector_size(16), aligned(16)));

__device__ __forceinline__ void decode(uint32_t e, uint32_t& p, uint32_t& row,
                                       uint32_t& col, uint32_t& width)
{
    if (e < 6u * N1) {
        p = e / N1;
        const uint32_t rem = e - p * N1;
        row = rem / W1;
        col = rem - row * W1;
        width = W1;
    } else {
        const uint32_t q  = e - 6u * N1;
        const uint32_t pp = q / N2;
        const uint32_t rem = q - pp * N2;
        p = 6u + pp;
        row = rem / W2;
        col = rem - row * W2;
        width = W2;
    }
}

__device__ __forceinline__ unsigned pack8(const i4a& v, const i4a& x) {
    return (unsigned)(v[0] | (v[1] << 2) | (v[2] << 4) | (v[3] << 6)
                    | (x[0] << 8) | (x[1] << 10) | (x[2] << 12) | (x[3] << 14));
}

// ---- motif formulas on 2-bit-packed stone masks (cell k at bits 2k..2k+1);
//      output for cell k lands at bit 2k. Same expressions as verified R12.
__device__ __forceinline__ unsigned bamboo_f(unsigned S0, unsigned S1,
                                             unsigned E0, unsigned E1) {
    const unsigned Dg = S0 & (S1 >> 2), Ag = (S0 >> 2) & S1;
    return (Dg & ((E0 >> 2) & E1)) | (Ag & (E0 & (E1 >> 2)));
}
__device__ __forceinline__ unsigned tiger_f(unsigned S0, unsigned S1,
                                            unsigned anyE) {
    const unsigned s0 = S0 >> 2, s1 = S1 >> 2;
    return ((S0 & s0) | (S1 & s1) | (S0 & s1) | (s0 & S1)
          | (S0 & S1) | (s0 & s1)) & anyE;
}
__device__ __forceinline__ unsigned etri_f(unsigned S0, unsigned S1,
                                           unsigned anyE) {
    const unsigned s0 = S0 >> 2, s1 = S1 >> 2;
    return (((S0 & s0) & (S1 | s1)) | ((S1 & s1) & (S0 | s0))) & anyE;
}

// scalar single-output evaluation (rare path; verified in R15)
__device__ __forceinline__ int one_out(const int* __restrict__ board,
                                       uint32_t p, uint32_t row, uint32_t col)
{
    if (p < 6u) {
        const int a = board[(size_t)row * BW + col];
        const int b = board[(size_t)row * BW + col + 1];
        const int c = board[(size_t)(row + 1) * BW + col];
        const int d = board[(size_t)(row + 1) * BW + col + 1];
        const int nb = (a == 1) + (b == 1) + (c == 1) + (d == 1);
        const int nw = (a == 2) + (b == 2) + (c == 2) + (d == 2);
        const int ne = 4 - nb - nw;
        switch (p) {
        case 0: return ((a==1 && d==1 && b==0 && c==0) || (b==1 && c==1 && a==0 && d==0));
        case 1: return ((a==2 && d==2 && b==0 && c==0) || (b==2 && c==2 && a==0 && d==0));
        case 2: return (nb >= 2 && ne >= 1);
        case 3: return (nw >= 2 && ne >= 1);
        case 4: return (nb == 3 && ne == 1);
        default: return (nw == 3 && ne == 1);
        }
    }
    const int st = (p == 6u) ? 1 : 2;
    const size_t r1 = (size_t)(row + 1) * BW;
    return (board[r1 + col + 1] == 0
         && board[(size_t)row * BW + col + 1] == st
         && board[(size_t)(row + 2) * BW + col + 1] == st
         && board[r1 + col] == st
         && board[r1 + col + 2] == st);
}

__global__ __launch_bounds__(256)
void direct_kernel(const int* __restrict__ board, int* __restrict__ out)
{
    const uint32_t c = blockIdx.x * 256u + threadIdx.x;  // chunk of 4 ints
    const uint32_t o = c * 4u;
    if (o >= TOTAL) return;

    uint32_t p, row, col, width;
    decode(o, p, row, col, width);

    if (col + 3u < width && o + 4u <= TOTAL) {
        // common case: 4 outputs in one row of one plane; c4 wave-uniform.
        const uint32_t c4 = col & 3u;
        const uint32_t sh = 2u * c4;
        const int* b0 = board + (size_t)row * BW + (col - c4);  // 16B aligned
        unsigned w;

        if (p < 6u) {
            // rows row, row+1: two aligned 16B chunks each (never cross row end:
            // window base advances in steps of 4 from c4 -> chunk2 ends <= 4095)
            const i4a a0 = *(const i4a*)b0;
            const i4a a1 = *(const i4a*)(b0 + 4);
            const i4a d0 = *(const i4a*)(b0 + BW);
            const i4a d1 = *(const i4a*)(b0 + BW + 4);
            const unsigned f0 = pack8(a0, a1) >> sh;   // cells col..col+(7-c4)
            const unsigned f1 = pack8(d0, d1) >> sh;

            const unsigned B0 = f0 & M55, Wt = (f0 >> 1) & M55;
            const unsigned B1 = f1 & M55, Wl = (f1 >> 1) & M55;
            const unsigned E0 = (B0 | Wt) ^ M55;
            const unsigned E1 = (B1 | Wl) ^ M55;
            const unsigned anyE = E0 | (E0 >> 2) | E1 | (E1 >> 2);

            switch (p) {                 // wave-uniform branch
            case 0:  w = bamboo_f(B0, B1, E0, E1); break;
            case 1:  w = bamboo_f(Wt, Wl, E0, E1); break;
            case 2:  w = tiger_f(B0, B1, anyE);    break;
            case 3:  w = tiger_f(Wt, Wl, anyE);    break;
            case 4:  w = etri_f(B0, B1, anyE);     break;
            default: w = etri_f(Wt, Wl, anyE);     break;
            }
        } else {
            // eyes: rows row..row+2. Top/bottom need cells col+1..col+4 (in the
            // 2-chunk window for all c4); middle needs col..col+5 -> one extra
            // dword (cell col+5 = bm[8]) only when c4==3 (wave-uniform).
            const int* bm = b0 + BW;
            const int* bb = b0 + 2 * BW;
            const i4a a0 = *(const i4a*)b0;
            const i4a a1 = *(const i4a*)(b0 + 4);
            const i4a m0 = *(const i4a*)bm;
            const i4a m1 = *(const i4a*)(bm + 4);
            const i4a g0 = *(const i4a*)bb;
            const i4a g1 = *(const i4a*)(bb + 4);
            const unsigned f0 = pack8(a0, a1) >> sh;
            unsigned       f1 = pack8(m0, m1) >> sh;
            const unsigned f2 = pack8(g0, g1) >> sh;
            if (c4 == 3u) f1 |= ((unsigned)bm[8]) << 10;  // cell col+5 (in-row)

            const unsigned B1 = f1 & M55, Wl = (f1 >> 1) & M55;
            const unsigned E1 = (B1 | Wl) ^ M55;
            const unsigned sE1 = E1 >> 2;
            if (p == 6u) {
                const unsigned sB0 = (f0 & M55) >> 2;
                const unsigned sB2 = (f2 & M55) >> 2;
                w = sE1 & sB0 & B1 & (B1 >> 4) & sB2;
            } else {
                const unsigned sW0 = ((f0 >> 1) & M55) >> 2;
                const unsigned sW2 = ((f2 >> 1) & M55) >> 2;
                w = sE1 & sW0 & Wl & (Wl >> 4) & sW2;
            }
        }

        i4a s;
        s[0] = (int)(w & 1u);
        s[1] = (int)((w >> 2) & 1u);
        s[2] = (int)((w >> 4) & 1u);
        s[3] = (int)((w >> 6) & 1u);
        *(i4a*)(out + o) = s;            // 16B chunk of an aligned 1KB/wave block
    } else {
        // rare (~0.1%): row/plane crossing or final partial chunk
        int vals[4];
        #pragma unroll
        for (int k = 0; k < 4; ++k) {
            const uint32_t e = o + (uint32_t)k;
            if (e < TOTAL) {
                uint32_t pp, rr, cc, ww;
                decode(e, pp, rr, cc, ww);
                vals[k] = one_out(board, pp, rr, cc);
            } else vals[k] = 0;
        }
        if (o + 4u <= TOTAL) {
            i4a s; s[0] = vals[0]; s[1] = vals[1]; s[2] = vals[2]; s[3] = vals[3];
            *(i4a*)(out + o) = s;
        } else {
            for (uint32_t k = 0; o + k < TOTAL; ++k) out[o + k] = vals[k];
        }
    }
}

extern "C" void kernel_launch(void* const* d_in, const int* in_sizes, int n_in,
                              void* d_out, int out_size, void* d_ws, size_t ws_size,
                              hipStream_t stream) {
    const int* board = (const int*)d_in[0];
    int* out = (int*)d_out;

    const uint32_t chunks  = (TOTAL + 3u) / 4u;      // 33,533,956
    const uint32_t nblocks = (chunks + 255u) / 256u; // 130,993
    direct_kernel<<<dim3(nblocks, 1, 1), dim3(256, 1, 1), 0, stream>>>(board, out);
}

// Round 7
// 579.185 us; speedup vs baseline: 1.1419x; 1.1345x over previous
//
#include <hip/hip_runtime.h>
#include <cstdint>

// Board: 4096 x 4096 int32 in {0,1,2}  (0=empty, 1=black, 2=white)
// Outputs BOOLEAN -> int32 (0/1), concatenated flat in d_out:
//   bamboo_b, bamboo_w, tiger_b, tiger_w, etri_b, etri_w  -> each (4095,4095)
//   eye_b, eye_w                                          -> each (4094,4094)
//
// R17 = restore R14 (session-best, 578.2 us, passed).
//   Evidence box after R15/R16: store alignment is NOT the lever (perfect
//   1KB/wave aligned stores lost to scattered 16B-aligned by 65 us); flat
//   output mapping loses via 8x board re-read; tiled structure is at minimum
//   store count, minimum read traffic, ~8 us VALU. All named mechanisms for
//   the gap vs the 6.3 TB/s fill have been tested and eliminated.
//   ws_size >= 16 MB -> pack+expand via d_ws; else R12 tiled kernel.

#define BW 4096
#define W1 4095
#define W2 4094
#define N1 16769025u
#define N2 16760836u
#define TOTAL 134135822u        // 6*N1 + 2*N2
#define PS 524160u              // words per plane: 4095 rows * 128
#define NEED_BYTES 16773120u    // 8 * PS * 4
#define M55 0x5555u

typedef int i4a __attribute__((vector_size(16), aligned(16)));

struct Planes { unsigned pm[6]; unsigned em[2]; };

// m0/m1/m2: packed rows i, i+1, i+2 (2-bit fields, pos k at bits 2k..2k+1)
__device__ __forceinline__ Planes compute_swar(unsigned m0, unsigned m1, unsigned m2)
{
    const unsigned B0 = m0 & M55,        Wt = (m0 >> 1) & M55;
    const unsigned B1 = m1 & M55,        Wl = (m1 >> 1) & M55;
    const unsigned B2 = m2 & M55,        Wb = (m2 >> 1) & M55;
    const unsigned E0 = (B0 | Wt) ^ M55;
    const unsigned E1 = (B1 | Wl) ^ M55;

    const unsigned sB0 = B0 >> 2, sB1 = B1 >> 2;
    const unsigned sW0 = Wt >> 2, sW1 = Wl >> 2;
    const unsigned sE0 = E0 >> 2, sE1 = E1 >> 2;
    const unsigned sB2 = B2 >> 2, sW2 = Wb >> 2;

    const unsigned EaEd = E0 & sE1;              // diag pair both empty
    const unsigned EbEc = sE0 & E1;              // anti pair both empty
    const unsigned anyE = E0 | sE0 | E1 | sE1;   // >=1 empty corner

    Planes r;
    {   // black
        const unsigned P = B0 & sB0, Q = B1 & sB1;
        const unsigned Dg = B0 & sB1, Ag = sB0 & B1;
        const unsigned X = B0 & B1,  Y = sB0 & sB1;
        const unsigned ge2 = P | Q | Dg | Ag | X | Y;
        const unsigned ge3 = (P & (B1 | sB1)) | (Q & (B0 | sB0));
        r.pm[0] = (Dg & EbEc) | (Ag & EaEd);   // bamboo_b
        r.pm[2] = ge2 & anyE;                  // tiger_b
        r.pm[4] = ge3 & anyE;                  // etri_b
        r.em[0] = sE1 & sB0 & B1 & (B1 >> 4) & sB2;  // eye_b
    }
    {   // white
        const unsigned P = Wt & sW0, Q = Wl & sW1;
        const unsigned Dg = Wt & sW1, Ag = sW0 & Wl;
        const unsigned X = Wt & Wl,  Y = sW0 & sW1;
        const unsigned ge2 = P | Q | Dg | Ag | X | Y;
        const unsigned ge3 = (P & (Wl | sW1)) | (Q & (Wt | sW0));
        r.pm[1] = (Dg & EbEc) | (Ag & EaEd);
        r.pm[3] = ge2 & anyE;
        r.pm[5] = ge3 & anyE;
        r.em[1] = sE1 & sW0 & Wl & (Wl >> 4) & sW2;  // eye_w
    }
    return r;
}

// ---------------------------------------------------------------- fast path

// compress bits 0,2,4,6 of x into a 4-bit nibble
__device__ __forceinline__ unsigned nib4(unsigned x) {
    unsigned t = x & 0x55u;
    t = (t | (t >> 1)) & 0x33u;
    t = (t | (t >> 2)) & 0x0Fu;
    return t;
}

__global__ __launch_bounds__(256)
void pack_kernel(const int* __restrict__ board, uint32_t* __restrict__ bits)
{
    __shared__ uint8_t nib[32][256];   // [plane-row r*8+p][thread] 4-bit masks
    const int tid = threadIdx.x;
    const int u   = blockIdx.x * 256 + tid;   // 0..1023 (cols 4u..4u+3)
    const int i0  = blockIdx.y << 2;          // 0,4,...,4092
    const int base = u << 2;
    const bool fullv = (u < 1023);

    const int* pr6[6];
    #pragma unroll
    for (int j = 0; j < 6; ++j) {
        int r = i0 + j; if (r > W1) r = W1;
        pr6[j] = board + (size_t)r * BW + base;
    }
    i4a v[6], x[6];
    #pragma unroll
    for (int j = 0; j < 6; ++j) v[j] = *(const i4a*)pr6[j];
    #pragma unroll
    for (int j = 0; j < 6; ++j) x[j] = (i4a){0,0,0,0};
    if (fullv) {
        #pragma unroll
        for (int j = 0; j < 6; ++j) x[j] = *(const i4a*)(pr6[j] + 4);
    }

    auto pack = [](const i4a& vv, const i4a& xx) -> unsigned {
        return (unsigned)(vv[0] | (vv[1] << 2) | (vv[2] << 4) | (vv[3] << 6)
                        | (xx[0] << 8) | (xx[1] << 10) | (xx[2] << 12) | (xx[3] << 14));
    };
    unsigned m[6];
    #pragma unroll
    for (int j = 0; j < 6; ++j) m[j] = pack(v[j], x[j]);

    // 4 output rows, 8 planes each -> 4-bit nibble (cols 4u..4u+3)
    #pragma unroll
    for (int r = 0; r < 4; ++r) {
        Planes P = compute_swar(m[r], m[r + 1], m[r + 2]);
        #pragma unroll
        for (int p = 0; p < 6; ++p) nib[r * 8 + p][tid] = (uint8_t)nib4(P.pm[p]);
        nib[r * 8 + 6][tid] = (uint8_t)nib4(P.em[0]);
        nib[r * 8 + 7][tid] = (uint8_t)nib4(P.em[1]);
    }
    __syncthreads();

    // pack 8 nibbles -> one 32-bit word; block covers words bx*32 .. bx*32+31
    #pragma unroll
    for (int k = 0; k < 4; ++k) {
        const int wg  = tid + 256 * k;        // 0..1023
        const int pr  = wg >> 5, w_in = wg & 31;
        const int r   = pr >> 3, p = pr & 7;
        const int row = i0 + r;
        const bool valid = (p < 6) ? (row <= 4094) : (row <= 4093);
        if (valid) {
            uint64_t t = *(const uint64_t*)&nib[pr][w_in * 8];
            t &= 0x0F0F0F0F0F0F0F0Full;
            t = (t | (t >> 4))  & 0x00FF00FF00FF00FFull;
            t = (t | (t >> 8))  & 0x0000FFFF0000FFFFull;
            t = (t | (t >> 16));
            bits[(size_t)p * PS + (size_t)row * 128u
                 + (unsigned)(blockIdx.x * 32 + w_in)] = (uint32_t)t;
        }
    }
}

__device__ __forceinline__ void decode(uint32_t e, uint32_t& p, uint32_t& row,
                                       uint32_t& col, uint32_t& width)
{
    if (e < 6u * N1) {
        p = e / N1;
        const uint32_t rem = e - p * N1;
        row = rem / W1;
        col = rem - row * W1;
        width = W1;
    } else {
        const uint32_t q  = e - 6u * N1;
        const uint32_t pp = q / N2;
        const uint32_t rem = q - pp * N2;
        p = 6u + pp;
        row = rem / W2;
        col = rem - row * W2;
        width = W2;
    }
}

__global__ __launch_bounds__(256)
void expand_kernel(const uint32_t* __restrict__ bits, int* __restrict__ out)
{
    const uint32_t c = blockIdx.x * 256u + threadIdx.x;  // chunk of 4 ints
    const uint32_t o = c * 4u;
    if (o >= TOTAL) return;

    uint32_t p, row, col, width;
    decode(o, p, row, col, width);

    if (col + 3u < width && o + 4u <= TOTAL) {           // common: no row cross
        const uint32_t* wrow = bits + p * PS + row * 128u;
        const uint32_t lo = col >> 5, sh = col & 31u;
        const uint32_t w0 = wrow[lo];
        const uint32_t w1 = wrow[lo + 1];   // in bits[] bounds; used iff sh>=29
        const uint32_t bv = (uint32_t)(((uint64_t)w0 | ((uint64_t)w1 << 32)) >> sh);
        i4a s;
        s[0] = (int)(bv & 1u);
        s[1] = (int)((bv >> 1) & 1u);
        s[2] = (int)((bv >> 2) & 1u);
        s[3] = (int)((bv >> 3) & 1u);
        *(i4a*)(out + o) = s;                             // full-line aligned
    } else {                                              // rare: row crossing
        int vals[4];
        #pragma unroll
        for (int k = 0; k < 4; ++k) {
            const uint32_t e = o + (uint32_t)k;
            if (e < TOTAL) {
                uint32_t pp, rr, cc, ww;
                decode(e, pp, rr, cc, ww);
                vals[k] = (int)((bits[pp * PS + rr * 128u + (cc >> 5)] >> (cc & 31u)) & 1u);
            } else vals[k] = 0;
        }
        if (o + 4u <= TOTAL) {
            i4a s; s[0] = vals[0]; s[1] = vals[1]; s[2] = vals[2]; s[3] = vals[3];
            *(i4a*)(out + o) = s;
        } else {
            for (uint32_t k = 0; o + k < TOTAL; ++k) out[o + k] = vals[k];
        }
    }
}

// ------------------------------------------------------ fallback (R12 path)

template<int PH>   // PH = i & 3
__device__ __forceinline__ void store_row(
    int* __restrict__ out, const int i, const int u, const bool has2,
    const Planes& pl)
{
    const bool fullv = (u < 1023);
    const size_t orow = (size_t)i * W1 + (u << 2);

    #pragma unroll
    for (int p = 0; p < 6; ++p) {
        const int sp = (PH - p) & 3;           // compile-time
        int* dst = out + (size_t)p * N1 + orow;
        if (fullv) {
            i4a s;
            s[0] = (int)((pl.pm[p] >> (2 * (sp + 0))) & 1);
            s[1] = (int)((pl.pm[p] >> (2 * (sp + 1))) & 1);
            s[2] = (int)((pl.pm[p] >> (2 * (sp + 2))) & 1);
            s[3] = (int)((pl.pm[p] >> (2 * (sp + 3))) & 1);
            *(i4a*)(dst + sp) = s;
        } else {
            #pragma unroll
            for (int k = 0; k < 3 - sp; ++k)
                dst[sp + k] = (int)((pl.pm[p] >> (2 * (sp + k))) & 1);
        }
        if (u == 0) {
            #pragma unroll
            for (int k = 0; k < sp; ++k)
                dst[k] = (int)((pl.pm[p] >> (2 * k)) & 1);
        }
    }

    if (has2) {
        const int e = (PH & 1) ? 0 : 2;
        int* d0 = out + (size_t)6 * N1 + (size_t)i * W2 + (u << 2);
        int* d1 = d0 + N2;
        if (fullv) {
            i4a s0, s1;
            #pragma unroll
            for (int k = 0; k < 4; ++k) {
                s0[k] = (int)((pl.em[0] >> (2 * (e + k))) & 1);
                s1[k] = (int)((pl.em[1] >> (2 * (e + k))) & 1);
            }
            *(i4a*)(d0 + e) = s0;
            *(i4a*)(d1 + e) = s1;
        } else if (e == 0) {
            #pragma unroll
            for (int k = 0; k < 2; ++k) {
                d0[k] = (int)((pl.em[0] >> (2 * k)) & 1);
                d1[k] = (int)((pl.em[1] >> (2 * k)) & 1);
            }
        }
        if (u == 0) {
            #pragma unroll
            for (int k = 0; k < e; ++k) {
                d0[k] = (int)((pl.em[0] >> (2 * k)) & 1);
                d1[k] = (int)((pl.em[1] >> (2 * k)) & 1);
            }
        }
    }
}

__global__ __launch_bounds__(256)
void motif_kernel(const int* __restrict__ board, int* __restrict__ out) {
    const int u  = blockIdx.x * 256 + threadIdx.x;  // 0..1023
    const int i0 = blockIdx.y << 2;                 // 0,4,...,4092
    const int base = u << 2;
    const bool fullv = (u < 1023);
    const bool last = (i0 == W1 - 3);               // i0 == 4092

    const int* pr[6];
    #pragma unroll
    for (int j = 0; j < 6; ++j) {
        int r = i0 + j; if (r > W1) r = W1;
        pr[j] = board + (size_t)r * BW + base;
    }
    i4a v[6], x[6];
    #pragma unroll
    for (int j = 0; j < 6; ++j) v[j] = *(const i4a*)pr[j];
    #pragma unroll
    for (int j = 0; j < 6; ++j) x[j] = (i4a){0,0,0,0};
    if (fullv) {
        #pragma unroll
        for (int j = 0; j < 6; ++j) x[j] = *(const i4a*)(pr[j] + 4);
    }

    auto pack = [](const i4a& vv, const i4a& xx) -> unsigned {
        return (unsigned)(vv[0] | (vv[1] << 2) | (vv[2] << 4) | (vv[3] << 6)
                        | (xx[0] << 8) | (xx[1] << 10) | (xx[2] << 12) | (xx[3] << 14));
    };
    unsigned m[6];
    #pragma unroll
    for (int j = 0; j < 6; ++j) m[j] = pack(v[j], x[j]);

    {   Planes P = compute_swar(m[0], m[1], m[2]);
        store_row<0>(out, i0, u, true, P); }
    {   Planes P = compute_swar(m[1], m[2], m[3]);
        store_row<1>(out, i0 + 1, u, true, P); }
    {   Planes P = compute_swar(m[2], m[3], m[4]);
        store_row<2>(out, i0 + 2, u, !last, P); }
    if (!last) {
        Planes P = compute_swar(m[3], m[4], m[5]);
        store_row<3>(out, i0 + 3, u, true, P); }
}

// -----------------------------------------------------------------

extern "C" void kernel_launch(void* const* d_in, const int* in_sizes, int n_in,
                              void* d_out, int out_size, void* d_ws, size_t ws_size,
                              hipStream_t stream) {
    const int* board = (const int*)d_in[0];
    int* out = (int*)d_out;

    if (d_ws != nullptr && ws_size >= (size_t)NEED_BYTES) {
        // fast path: bitboard in workspace
        uint32_t* bits = (uint32_t*)d_ws;
        pack_kernel<<<dim3(4, 1024, 1), dim3(256, 1, 1), 0, stream>>>(board, bits);
        const uint32_t chunks = (TOTAL + 3u) / 4u;       // 33,533,956
        const uint32_t eblocks = (chunks + 255u) / 256u; // 130,993
        expand_kernel<<<dim3(eblocks, 1, 1), dim3(256, 1, 1), 0, stream>>>(bits, out);
    } else {
        // safe fallback: R12 tiled kernel (no scratch needed)
        motif_kernel<<<dim3(4, 1024, 1), dim3(256, 1, 1), 0, stream>>>(board, out);
    }
}